// Round 4
// baseline (498.835 us; speedup 1.0000x reference)
//
#include <hip/hip_runtime.h>
#include <cstdint>
#include <cstddef>

// Problem constants (static per reference)
#define NT 2048    // tokens S
#define HD 1024    // hidden H
#define FD 4096    // ffn F
#define NE 8       // experts
#define CAP 512    // capacity = ceil(S*2*1.0/8)
#define KSPLIT 4   // split-K factor for GEMM2

typedef __bf16 bf16x8_t __attribute__((ext_vector_type(8)));
typedef float f32x4_t __attribute__((ext_vector_type(4)));

typedef const __attribute__((address_space(1))) void* as1_cvp;
typedef __attribute__((address_space(3))) void* as3_vp;

__device__ __forceinline__ void load_lds16(const void* g, void* s) {
  __builtin_amdgcn_global_load_lds((as1_cvp)g, (as3_vp)s, 16, 0, 0);
}

__device__ __forceinline__ unsigned short f2bf(float f) {
  unsigned int u = __float_as_uint(f);
  unsigned int r = (u + 0x7fffu + ((u >> 16) & 1u)) >> 16;  // RNE
  return (unsigned short)r;
}

// gelu_tanh(x) = 0.5x(1+tanh(0.79788456(x+0.044715x^3))) = x*sigmoid(2z)
//             = x / (1 + exp2(-2.3022077*(x+0.044715x^3)))
// HW v_exp_f32 + v_rcp_f32: ~1ulp vs libm tanhf path, 5x fewer VALU ops.
__device__ __forceinline__ float gelu_fast(float x) {
  float u = x + 0.044715f * x * x * x;
  float t = __builtin_amdgcn_exp2f(-2.3022077f * u);
  return x * __builtin_amdgcn_rcpf(1.0f + t);
}

// ---------------- gating: 4 waves/block, one token per wave ----------------
__global__ __launch_bounds__(256) void gating_kernel(
    const float* __restrict__ x, const float* __restrict__ wg,
    float* __restrict__ gates, int* __restrict__ idx1, int* __restrict__ idx2,
    float* __restrict__ gate1, float* __restrict__ gate2)
{
  int s = blockIdx.x * 4 + (threadIdx.x >> 6);
  int lane = threadIdx.x & 63;
  const float* xs = x + (size_t)s * HD;
  float acc[NE];
  #pragma unroll
  for (int e = 0; e < NE; ++e) acc[e] = 0.f;
  #pragma unroll
  for (int i = 0; i < HD / 64; ++i) {
    int h = i * 64 + lane;
    float xv = xs[h];
    const float4 w0 = *(const float4*)(wg + (size_t)h * NE);
    const float4 w1 = *(const float4*)(wg + (size_t)h * NE + 4);
    acc[0] += xv * w0.x; acc[1] += xv * w0.y; acc[2] += xv * w0.z; acc[3] += xv * w0.w;
    acc[4] += xv * w1.x; acc[5] += xv * w1.y; acc[6] += xv * w1.z; acc[7] += xv * w1.w;
  }
  #pragma unroll
  for (int off = 32; off > 0; off >>= 1) {
    #pragma unroll
    for (int e = 0; e < NE; ++e) acc[e] += __shfl_down(acc[e], off);
  }
  if (lane == 0) {
    float m = acc[0];
    #pragma unroll
    for (int e = 1; e < NE; ++e) m = fmaxf(m, acc[e]);
    float p[NE]; float sum = 0.f;
    #pragma unroll
    for (int e = 0; e < NE; ++e) { p[e] = expf(acc[e] - m); sum += p[e]; }
    float inv = 1.0f / sum;
    // argmax over logits, first-index tie-break (matches jnp.argmax)
    int i1 = 0; float b1 = acc[0];
    #pragma unroll
    for (int e = 1; e < NE; ++e) if (acc[e] > b1) { b1 = acc[e]; i1 = e; }
    int i2 = (i1 == 0) ? 1 : 0; float b2 = acc[i2];
    #pragma unroll
    for (int e = 0; e < NE; ++e) if (e != i1 && acc[e] > b2) { b2 = acc[e]; i2 = e; }
    #pragma unroll
    for (int e = 0; e < NE; ++e) gates[(size_t)s * NE + e] = p[e] * inv;
    idx1[s] = i1; idx2[s] = i2;
    gate1[s] = p[i1] * inv;
    gate2[s] = p[i2] * inv;
  }
}

// ------------- scan: single block, wave w owns expert w -------------
__global__ __launch_bounds__(512) void scan_kernel(
    const int* __restrict__ idx1, const int* __restrict__ idx2,
    const float* __restrict__ gate1, const float* __restrict__ gate2,
    const float* __restrict__ gates,
    int* __restrict__ loc1a, int* __restrict__ loc2a,
    float* __restrict__ g1a, float* __restrict__ g2a,
    int* __restrict__ slot1a, int* __restrict__ slot2a,
    int* __restrict__ slot_tok, float* __restrict__ out_tail)
{
  __shared__ int cnt1[NE];
  __shared__ float gsum[NE];
  __shared__ int i1s[NT];
  __shared__ int i2s[NT];
  int tid = threadIdx.x;
  for (int i = tid; i < NE * CAP; i += 512) slot_tok[i] = -1;
  for (int i = tid; i < NT; i += 512) { i1s[i] = idx1[i]; i2s[i] = idx2[i]; }
  if (tid < NE) gsum[tid] = 0.f;
  __syncthreads();
  int w = tid >> 6, lane = tid & 63;
  unsigned long long below = (1ull << lane) - 1ull;

  // cumsum(mask1) per expert via ballot prefix
  int run = 0;
  for (int c = 0; c < NT / 64; ++c) {
    int s = c * 64 + lane;
    bool m = (i1s[s] == w);
    unsigned long long bal = __ballot(m);
    if (m) loc1a[s] = run + (int)__popcll(bal & below);
    run += (int)__popcll(bal);
  }
  if (lane == 0) cnt1[w] = run;
  // cumsum(mask2) offset by full (pre-drop) count1 of same expert
  int run2 = run;
  for (int c = 0; c < NT / 64; ++c) {
    int s = c * 64 + lane;
    bool m = (i2s[s] == w);
    unsigned long long bal = __ballot(m);
    if (m) loc2a[s] = run2 + (int)__popcll(bal & below);
    run2 += (int)__popcll(bal);
  }
  __syncthreads();

  // capacity drop, gate renorm, slot maps
  for (int s = tid; s < NT; s += 512) {
    int e1 = i1s[s], e2 = i2s[s];
    int l1 = loc1a[s], l2 = loc2a[s];
    bool k1 = (l1 < CAP), k2 = (l2 < CAP);
    float g1r = k1 ? gate1[s] : 0.f;
    float g2r = k2 ? gate2[s] : 0.f;
    float denom = fmaxf(g1r + g2r, 1.1920929e-07f);
    g1a[s] = g1r / denom;
    g2a[s] = g2r / denom;
    int s1 = k1 ? (e1 * CAP + l1) : -1;
    int s2 = k2 ? (e2 * CAP + l2) : -1;
    slot1a[s] = s1; slot2a[s] = s2;
    if (s1 >= 0) slot_tok[s1] = s;
    if (s2 >= 0) slot_tok[s2] = s;
  }

  // aux loss: sum of gates per expert
  float part[NE];
  #pragma unroll
  for (int e = 0; e < NE; ++e) part[e] = 0.f;
  for (int s = tid; s < NT; s += 512) {
    const float* gr = gates + (size_t)s * NE;
    #pragma unroll
    for (int e = 0; e < NE; ++e) part[e] += gr[e];
  }
  #pragma unroll
  for (int e = 0; e < NE; ++e) atomicAdd(&gsum[e], part[e]);
  __syncthreads();
  if (tid == 0) {
    float laux = 0.f;
    #pragma unroll
    for (int e = 0; e < NE; ++e)
      laux += (gsum[e] / (float)NT) * ((float)cnt1[e] / (float)NT);
    laux *= (float)(NE * NE) * 0.01f;
    out_tail[0] = laux;
  }
  if (tid < NE) out_tail[1 + tid] = (float)cnt1[tid];
}

// ------------- merged weight transpose: [K,N] fp32 -> [N,K] bf16 -------------
// z<NE: w1 expert z (K=HD,N=FD); z>=NE: w2 expert z-NE (K=FD,N=HD).
// Read: float4 coalesced (256B/row-segment). LDS 64x65 pad: write banks
// (r+c)%32 and read banks (kc+j+nr)%32 are both exact 2-way (free, m136).
// Write: uint4 = 8 bf16 along K -> 128B contiguous per output row.
__global__ __launch_bounds__(256) void transpose_both_kernel(
    const float* __restrict__ w1, const float* __restrict__ w2,
    unsigned short* __restrict__ w1t, unsigned short* __restrict__ w2t)
{
  __shared__ float tile[64 * 65];
  const int z = blockIdx.z;
  const float* src; unsigned short* dst; int K, N, n0, k0;
  if (z < NE) {
    K = HD; N = FD;
    src = w1 + (size_t)z * K * N;
    dst = w1t + (size_t)z * K * N;
    n0 = blockIdx.x * 64; k0 = blockIdx.y * 64;
  } else {
    K = FD; N = HD;
    src = w2 + (size_t)(z - NE) * K * N;
    dst = w2t + (size_t)(z - NE) * K * N;
    n0 = blockIdx.y * 64; k0 = blockIdx.x * 64;
  }
  const int tid = threadIdx.x;
  #pragma unroll
  for (int i = 0; i < 4; ++i) {
    int task = i * 256 + tid;
    int r = task >> 4, c = (task & 15) * 4;
    float4 v = *(const float4*)(src + (size_t)(k0 + r) * N + n0 + c);
    tile[r * 65 + c + 0] = v.x;
    tile[r * 65 + c + 1] = v.y;
    tile[r * 65 + c + 2] = v.z;
    tile[r * 65 + c + 3] = v.w;
  }
  __syncthreads();
  #pragma unroll
  for (int i = 0; i < 2; ++i) {
    int task = i * 256 + tid;
    int nr = task >> 3, kc = (task & 7) * 8;
    const float* col = &tile[kc * 65 + nr];
    unsigned int b0 = f2bf(col[0 * 65]), b1 = f2bf(col[1 * 65]);
    unsigned int b2 = f2bf(col[2 * 65]), b3 = f2bf(col[3 * 65]);
    unsigned int b4 = f2bf(col[4 * 65]), b5 = f2bf(col[5 * 65]);
    unsigned int b6 = f2bf(col[6 * 65]), b7 = f2bf(col[7 * 65]);
    uint4 p;
    p.x = b0 | (b1 << 16);
    p.y = b2 | (b3 << 16);
    p.z = b4 | (b5 << 16);
    p.w = b6 | (b7 << 16);
    *(uint4*)(dst + (size_t)(n0 + nr) * K + k0 + kc) = p;
  }
}

// ------------- gather dispatched tokens -> bf16 A[E*C, H] -------------
__global__ __launch_bounds__(64) void gather_kernel(
    const float* __restrict__ x, const int* __restrict__ slot_tok,
    unsigned short* __restrict__ A)
{
  int slot = blockIdx.x;
  int t = slot_tok[slot];
  int tid = threadIdx.x;
  unsigned short* dst = A + (size_t)slot * HD;
  if (t >= 0) {
    const float* src = x + (size_t)t * HD;
    #pragma unroll
    for (int i = 0; i < 4; ++i) {
      int idx = i * 256 + tid * 4;
      float4 v = *(const float4*)(src + idx);
      uint2 p;
      p.x = (unsigned)f2bf(v.x) | ((unsigned)f2bf(v.y) << 16);
      p.y = (unsigned)f2bf(v.z) | ((unsigned)f2bf(v.w) << 16);
      *(uint2*)(dst + idx) = p;
    }
  } else {
    uint2 z; z.x = 0u; z.y = 0u;
    #pragma unroll
    for (int i = 0; i < 4; ++i) {
      int idx = i * 256 + tid * 4;
      *(uint2*)(dst + idx) = z;
    }
  }
}

// ------------- m97-style bf16 GEMM: C[M,N] = A[M,K] * BT[N,K]^T -------------
// GEMM1: blockIdx.z = expert; 128x128 tile, BK=32, global_load_lds w=16
__global__ __launch_bounds__(256) void gemm_bt_gelu_kernel(
    const unsigned short* __restrict__ A, const unsigned short* __restrict__ BT,
    unsigned short* __restrict__ Cout, int M, int N, int K)
{
  __shared__ unsigned short As[128 * 32];
  __shared__ unsigned short Bs[128 * 32];
  const int tid = threadIdx.x;
  const int w = tid >> 6, lane = tid & 63;
  const int wm = (w >> 1) * 64, wn = (w & 1) * 64;
  const int quad = lane >> 4, l15 = lane & 15;
  const int m0 = blockIdx.y * 128, n0 = blockIdx.x * 128;
  const size_t e = blockIdx.z;
  const unsigned short* Ae = A + e * (size_t)M * K;
  const unsigned short* Be = BT + e * (size_t)N * K;

  const int lin0 = tid, lin1 = 256 + tid;
  const unsigned short* ga0 = Ae + (size_t)(m0 + (lin0 >> 2)) * K + (lin0 & 3) * 8;
  const unsigned short* ga1 = Ae + (size_t)(m0 + (lin1 >> 2)) * K + (lin1 & 3) * 8;
  const unsigned short* gb0 = Be + (size_t)(n0 + (lin0 >> 2)) * K + (lin0 & 3) * 8;
  const unsigned short* gb1 = Be + (size_t)(n0 + (lin1 >> 2)) * K + (lin1 & 3) * 8;
  char* sa0 = (char*)As + w * 1024;
  char* sa1 = (char*)As + 4096 + w * 1024;
  char* sb0 = (char*)Bs + w * 1024;
  char* sb1 = (char*)Bs + 4096 + w * 1024;

  f32x4_t acc[4][4];
  f32x4_t zz = {0.f, 0.f, 0.f, 0.f};
  #pragma unroll
  for (int mi = 0; mi < 4; ++mi)
    #pragma unroll
    for (int ni = 0; ni < 4; ++ni) acc[mi][ni] = zz;

  const int aoff0 = (wm + l15) * 32 + quad * 8;  // ushort offsets
  const int boff0 = (wn + l15) * 32 + quad * 8;

  for (int kt = 0; kt < K; kt += 32) {
    load_lds16(ga0, sa0);
    load_lds16(ga1, sa1);
    load_lds16(gb0, sb0);
    load_lds16(gb1, sb1);
    ga0 += 32; ga1 += 32; gb0 += 32; gb1 += 32;
    __syncthreads();
    bf16x8_t af[4], bf[4];
    #pragma unroll
    for (int mi = 0; mi < 4; ++mi)
      af[mi] = *(const bf16x8_t*)(As + aoff0 + mi * 16 * 32);
    #pragma unroll
    for (int ni = 0; ni < 4; ++ni)
      bf[ni] = *(const bf16x8_t*)(Bs + boff0 + ni * 16 * 32);
    #pragma unroll
    for (int mi = 0; mi < 4; ++mi)
      #pragma unroll
      for (int ni = 0; ni < 4; ++ni)
        acc[mi][ni] = __builtin_amdgcn_mfma_f32_16x16x32_bf16(af[mi], bf[ni], acc[mi][ni], 0, 0, 0);
    __syncthreads();
  }

  // C/D layout: col = lane&15, row = quad*4 + r  [verified m89/m91]
  const size_t cbase = e * (size_t)M * N;
  #pragma unroll
  for (int mi = 0; mi < 4; ++mi) {
    int rowb = m0 + wm + mi * 16 + quad * 4;
    #pragma unroll
    for (int ni = 0; ni < 4; ++ni) {
      int col = n0 + wn + ni * 16 + l15;
      #pragma unroll
      for (int r = 0; r < 4; ++r) {
        float v = acc[mi][ni][r];
        size_t idx = cbase + (size_t)(rowb + r) * N + col;
        Cout[idx] = f2bf(gelu_fast(v));
      }
    }
  }
}

// GEMM2 with split-K: blockIdx.z = e*KSPLIT + sk. Partials -> Cpart[sk].
__global__ __launch_bounds__(256) void gemm2_splitk_kernel(
    const unsigned short* __restrict__ A, const unsigned short* __restrict__ BT,
    float* __restrict__ Cpart, int M, int N, int K)
{
  __shared__ unsigned short As[128 * 32];
  __shared__ unsigned short Bs[128 * 32];
  const int tid = threadIdx.x;
  const int w = tid >> 6, lane = tid & 63;
  const int wm = (w >> 1) * 64, wn = (w & 1) * 64;
  const int quad = lane >> 4, l15 = lane & 15;
  const int m0 = blockIdx.y * 128, n0 = blockIdx.x * 128;
  const size_t e = blockIdx.z >> 2;      // KSPLIT==4
  const int sk = blockIdx.z & 3;
  const int klen = K / KSPLIT;
  const int kb = sk * klen;
  const unsigned short* Ae = A + e * (size_t)M * K + kb;
  const unsigned short* Be = BT + e * (size_t)N * K + kb;

  const int lin0 = tid, lin1 = 256 + tid;
  const unsigned short* ga0 = Ae + (size_t)(m0 + (lin0 >> 2)) * K + (lin0 & 3) * 8;
  const unsigned short* ga1 = Ae + (size_t)(m0 + (lin1 >> 2)) * K + (lin1 & 3) * 8;
  const unsigned short* gb0 = Be + (size_t)(n0 + (lin0 >> 2)) * K + (lin0 & 3) * 8;
  const unsigned short* gb1 = Be + (size_t)(n0 + (lin1 >> 2)) * K + (lin1 & 3) * 8;
  char* sa0 = (char*)As + w * 1024;
  char* sa1 = (char*)As + 4096 + w * 1024;
  char* sb0 = (char*)Bs + w * 1024;
  char* sb1 = (char*)Bs + 4096 + w * 1024;

  f32x4_t acc[4][4];
  f32x4_t zz = {0.f, 0.f, 0.f, 0.f};
  #pragma unroll
  for (int mi = 0; mi < 4; ++mi)
    #pragma unroll
    for (int ni = 0; ni < 4; ++ni) acc[mi][ni] = zz;

  const int aoff0 = (wm + l15) * 32 + quad * 8;
  const int boff0 = (wn + l15) * 32 + quad * 8;

  for (int kt = 0; kt < klen; kt += 32) {
    load_lds16(ga0, sa0);
    load_lds16(ga1, sa1);
    load_lds16(gb0, sb0);
    load_lds16(gb1, sb1);
    ga0 += 32; ga1 += 32; gb0 += 32; gb1 += 32;
    __syncthreads();
    bf16x8_t af[4], bf[4];
    #pragma unroll
    for (int mi = 0; mi < 4; ++mi)
      af[mi] = *(const bf16x8_t*)(As + aoff0 + mi * 16 * 32);
    #pragma unroll
    for (int ni = 0; ni < 4; ++ni)
      bf[ni] = *(const bf16x8_t*)(Bs + boff0 + ni * 16 * 32);
    #pragma unroll
    for (int mi = 0; mi < 4; ++mi)
      #pragma unroll
      for (int ni = 0; ni < 4; ++ni)
        acc[mi][ni] = __builtin_amdgcn_mfma_f32_16x16x32_bf16(af[mi], bf[ni], acc[mi][ni], 0, 0, 0);
    __syncthreads();
  }

  float* Cp = Cpart + (size_t)sk * (NE * (size_t)M * N) + e * (size_t)M * N;
  #pragma unroll
  for (int mi = 0; mi < 4; ++mi) {
    int rowb = m0 + wm + mi * 16 + quad * 4;
    #pragma unroll
    for (int ni = 0; ni < 4; ++ni) {
      int col = n0 + wn + ni * 16 + l15;
      #pragma unroll
      for (int r = 0; r < 4; ++r) {
        Cp[(size_t)(rowb + r) * N + col] = acc[mi][ni][r];
      }
    }
  }
}

// ------------- combine: out[s] = g1*sum_p eop[slot1] + g2*sum_p eop[slot2] ----
__global__ __launch_bounds__(64) void combine_kernel(
    const float* __restrict__ eop, const float* __restrict__ g1a,
    const float* __restrict__ g2a, const int* __restrict__ slot1a,
    const int* __restrict__ slot2a, float* __restrict__ out)
{
  int s = blockIdx.x, tid = threadIdx.x;
  float g1 = g1a[s], g2 = g2a[s];
  int s1 = slot1a[s], s2 = slot2a[s];
  float m1 = (s1 < 0) ? 0.f : g1;
  float m2 = (s2 < 0) ? 0.f : g2;
  const float* r1 = eop + (size_t)(s1 < 0 ? 0 : s1) * HD;
  const float* r2 = eop + (size_t)(s2 < 0 ? 0 : s2) * HD;
  const size_t PSTRIDE = (size_t)NE * CAP * HD;
  #pragma unroll
  for (int i = 0; i < 4; ++i) {
    int idx = i * 256 + tid * 4;
    float ax = 0.f, ay = 0.f, az = 0.f, aw = 0.f;
    float bx = 0.f, by = 0.f, bz = 0.f, bw = 0.f;
    #pragma unroll
    for (int p = 0; p < KSPLIT; ++p) {
      float4 a = *(const float4*)(r1 + p * PSTRIDE + idx);
      float4 b = *(const float4*)(r2 + p * PSTRIDE + idx);
      ax += a.x; ay += a.y; az += a.z; aw += a.w;
      bx += b.x; by += b.y; bz += b.z; bw += b.w;
    }
    float4 o;
    o.x = m1 * ax + m2 * bx;
    o.y = m1 * ay + m2 * by;
    o.z = m1 * az + m2 * bz;
    o.w = m1 * aw + m2 * bw;
    *(float4*)(out + (size_t)s * HD + idx) = o;
  }
}

// ---------------- workspace layout (bytes) ----------------
#define OFF_GATES   ((size_t)0)            // 2048*8*4   = 65536
#define OFF_IDX1    ((size_t)65536)        // 8192
#define OFF_IDX2    ((size_t)73728)
#define OFF_GATE1   ((size_t)81920)
#define OFF_GATE2   ((size_t)90112)
#define OFF_LOC1    ((size_t)98304)
#define OFF_LOC2    ((size_t)106496)
#define OFF_G1      ((size_t)114688)
#define OFF_G2      ((size_t)122880)
#define OFF_SLOT1   ((size_t)131072)
#define OFF_SLOT2   ((size_t)139264)
#define OFF_SLOTTOK ((size_t)147456)       // 4096*4 = 16384
#define OFF_A       ((size_t)262144)       // 8*512*1024*2  = 8388608
#define OFF_H       ((size_t)8650752)      // 8*512*4096*2  = 33554432
#define OFF_W1T     ((size_t)42205184)     // 8*4096*1024*2 = 67108864  (reused as eo partials)
#define OFF_W2T     ((size_t)109314048)    // 8*1024*4096*2 = 67108864
#define WS_NEEDED   ((size_t)193200128)
#define OFF_EOPART  OFF_W1T                // 4 * 8*512*1024*4 = 67108864, exact fit

extern "C" void kernel_launch(void* const* d_in, const int* in_sizes, int n_in,
                              void* d_out, int out_size, void* d_ws, size_t ws_size,
                              hipStream_t stream) {
  (void)in_sizes; (void)n_in; (void)out_size;
  if (ws_size < WS_NEEDED) return;  // workspace too small: fail cleanly

  const float* x  = (const float*)d_in[0];
  const float* wg = (const float*)d_in[1];
  const float* w1 = (const float*)d_in[2];
  const float* w2 = (const float*)d_in[3];
  char* ws = (char*)d_ws;
  float* out = (float*)d_out;

  float* gates = (float*)(ws + OFF_GATES);
  int*   idx1  = (int*)(ws + OFF_IDX1);
  int*   idx2  = (int*)(ws + OFF_IDX2);
  float* gate1 = (float*)(ws + OFF_GATE1);
  float* gate2 = (float*)(ws + OFF_GATE2);
  int*   loc1  = (int*)(ws + OFF_LOC1);
  int*   loc2  = (int*)(ws + OFF_LOC2);
  float* g1a   = (float*)(ws + OFF_G1);
  float* g2a   = (float*)(ws + OFF_G2);
  int*   slot1 = (int*)(ws + OFF_SLOT1);
  int*   slot2 = (int*)(ws + OFF_SLOT2);
  int*   stok  = (int*)(ws + OFF_SLOTTOK);
  unsigned short* Abf  = (unsigned short*)(ws + OFF_A);
  unsigned short* hbuf = (unsigned short*)(ws + OFF_H);
  unsigned short* w1t  = (unsigned short*)(ws + OFF_W1T);
  unsigned short* w2t  = (unsigned short*)(ws + OFF_W2T);
  float* eopart = (float*)(ws + OFF_EOPART);  // aliases w1t (dead after GEMM1)

  // weights: [K,N] fp32 -> [N,K] bf16, both in one launch
  // z<8: w1 (K=HD,N=FD) -> 64 n-tiles x 16 k-tiles; z>=8: w2 swaps roles.
  transpose_both_kernel<<<dim3(64, 16, 2 * NE), 256, 0, stream>>>(w1, w2, w1t, w2t);

  gating_kernel<<<NT / 4, 256, 0, stream>>>(x, wg, gates, idx1, idx2, gate1, gate2);
  scan_kernel<<<1, 512, 0, stream>>>(idx1, idx2, gate1, gate2, gates,
                                     loc1, loc2, g1a, g2a, slot1, slot2, stok,
                                     out + (size_t)NT * HD);
  gather_kernel<<<NE * CAP, 64, 0, stream>>>(x, stok, Abf);

  // h = gelu(A @ w1): M=512 N=4096 K=1024, bf16 out
  gemm_bt_gelu_kernel<<<dim3(FD / 128, CAP / 128, NE), 256, 0, stream>>>(
      Abf, w1t, hbuf, CAP, FD, HD);
  // eo partials = h @ w2 (split-K=4): M=512 N=1024 K=4096, fp32 partials
  // NOTE: eopart aliases w1t, which is dead after GEMM1 completes (stream order)
  gemm2_splitk_kernel<<<dim3(HD / 128, CAP / 128, NE * KSPLIT), 256, 0, stream>>>(
      hbuf, w2t, eopart, CAP, HD, FD);

  combine_kernel<<<NT, 64, 0, stream>>>(eopart, g1a, g2a, slot1, slot2, out);
}

// Round 5
// 450.681 us; speedup vs baseline: 1.1068x; 1.1068x over previous
//
#include <hip/hip_runtime.h>
#include <cstdint>
#include <cstddef>

// Problem constants (static per reference)
#define NT 2048    // tokens S
#define HD 1024    // hidden H
#define FD 4096    // ffn F
#define NE 8       // experts
#define CAP 512    // capacity = ceil(S*2*1.0/8)
#define KSPLIT 4   // split-K factor for GEMM2

// B-tile LDS row stride (elems): 32 k-elems padded to 40 (80B) so that
// ds_write_b128/ds_read_b128 bank-starts (20n mod 32) cover all banks.
#define BROW 40

typedef __bf16 bf16x8_t __attribute__((ext_vector_type(8)));
typedef float f32x4_t __attribute__((ext_vector_type(4)));

typedef const __attribute__((address_space(1))) void* as1_cvp;
typedef __attribute__((address_space(3))) void* as3_vp;

__device__ __forceinline__ void load_lds16(const void* g, void* s) {
  __builtin_amdgcn_global_load_lds((as1_cvp)g, (as3_vp)s, 16, 0, 0);
}

__device__ __forceinline__ unsigned short f2bf(float f) {
  unsigned int u = __float_as_uint(f);
  unsigned int r = (u + 0x7fffu + ((u >> 16) & 1u)) >> 16;  // RNE
  return (unsigned short)r;
}

// gelu_tanh(x) = x / (1 + exp2(-2.3022077*(x+0.044715x^3)))  (~1ulp vs tanhf)
__device__ __forceinline__ float gelu_fast(float x) {
  float u = x + 0.044715f * x * x * x;
  float t = __builtin_amdgcn_exp2f(-2.3022077f * u);
  return x * __builtin_amdgcn_rcpf(1.0f + t);
}

// ---------------- gating: 4 waves/block, one token per wave ----------------
__global__ __launch_bounds__(256) void gating_kernel(
    const float* __restrict__ x, const float* __restrict__ wg,
    float* __restrict__ gates, int* __restrict__ idx1, int* __restrict__ idx2,
    float* __restrict__ gate1, float* __restrict__ gate2)
{
  int s = blockIdx.x * 4 + (threadIdx.x >> 6);
  int lane = threadIdx.x & 63;
  const float* xs = x + (size_t)s * HD;
  float acc[NE];
  #pragma unroll
  for (int e = 0; e < NE; ++e) acc[e] = 0.f;
  #pragma unroll
  for (int i = 0; i < HD / 64; ++i) {
    int h = i * 64 + lane;
    float xv = xs[h];
    const float4 w0 = *(const float4*)(wg + (size_t)h * NE);
    const float4 w1 = *(const float4*)(wg + (size_t)h * NE + 4);
    acc[0] += xv * w0.x; acc[1] += xv * w0.y; acc[2] += xv * w0.z; acc[3] += xv * w0.w;
    acc[4] += xv * w1.x; acc[5] += xv * w1.y; acc[6] += xv * w1.z; acc[7] += xv * w1.w;
  }
  #pragma unroll
  for (int off = 32; off > 0; off >>= 1) {
    #pragma unroll
    for (int e = 0; e < NE; ++e) acc[e] += __shfl_down(acc[e], off);
  }
  if (lane == 0) {
    float m = acc[0];
    #pragma unroll
    for (int e = 1; e < NE; ++e) m = fmaxf(m, acc[e]);
    float p[NE]; float sum = 0.f;
    #pragma unroll
    for (int e = 0; e < NE; ++e) { p[e] = expf(acc[e] - m); sum += p[e]; }
    float inv = 1.0f / sum;
    int i1 = 0; float b1 = acc[0];
    #pragma unroll
    for (int e = 1; e < NE; ++e) if (acc[e] > b1) { b1 = acc[e]; i1 = e; }
    int i2 = (i1 == 0) ? 1 : 0; float b2 = acc[i2];
    #pragma unroll
    for (int e = 0; e < NE; ++e) if (e != i1 && acc[e] > b2) { b2 = acc[e]; i2 = e; }
    #pragma unroll
    for (int e = 0; e < NE; ++e) gates[(size_t)s * NE + e] = p[e] * inv;
    idx1[s] = i1; idx2[s] = i2;
    gate1[s] = p[i1] * inv;
    gate2[s] = p[i2] * inv;
  }
}

// ------------- scan: single block, wave w owns expert w -------------
__global__ __launch_bounds__(512) void scan_kernel(
    const int* __restrict__ idx1, const int* __restrict__ idx2,
    const float* __restrict__ gate1, const float* __restrict__ gate2,
    const float* __restrict__ gates,
    int* __restrict__ loc1a, int* __restrict__ loc2a,
    float* __restrict__ g1a, float* __restrict__ g2a,
    int* __restrict__ slot1a, int* __restrict__ slot2a,
    int* __restrict__ slot_tok, float* __restrict__ out_tail)
{
  __shared__ int cnt1[NE];
  __shared__ float gsum[NE];
  __shared__ int i1s[NT];
  __shared__ int i2s[NT];
  int tid = threadIdx.x;
  for (int i = tid; i < NE * CAP; i += 512) slot_tok[i] = -1;
  for (int i = tid; i < NT; i += 512) { i1s[i] = idx1[i]; i2s[i] = idx2[i]; }
  if (tid < NE) gsum[tid] = 0.f;
  __syncthreads();
  int w = tid >> 6, lane = tid & 63;
  unsigned long long below = (1ull << lane) - 1ull;

  int run = 0;
  for (int c = 0; c < NT / 64; ++c) {
    int s = c * 64 + lane;
    bool m = (i1s[s] == w);
    unsigned long long bal = __ballot(m);
    if (m) loc1a[s] = run + (int)__popcll(bal & below);
    run += (int)__popcll(bal);
  }
  if (lane == 0) cnt1[w] = run;
  int run2 = run;
  for (int c = 0; c < NT / 64; ++c) {
    int s = c * 64 + lane;
    bool m = (i2s[s] == w);
    unsigned long long bal = __ballot(m);
    if (m) loc2a[s] = run2 + (int)__popcll(bal & below);
    run2 += (int)__popcll(bal);
  }
  __syncthreads();

  for (int s = tid; s < NT; s += 512) {
    int e1 = i1s[s], e2 = i2s[s];
    int l1 = loc1a[s], l2 = loc2a[s];
    bool k1 = (l1 < CAP), k2 = (l2 < CAP);
    float g1r = k1 ? gate1[s] : 0.f;
    float g2r = k2 ? gate2[s] : 0.f;
    float denom = fmaxf(g1r + g2r, 1.1920929e-07f);
    g1a[s] = g1r / denom;
    g2a[s] = g2r / denom;
    int s1 = k1 ? (e1 * CAP + l1) : -1;
    int s2 = k2 ? (e2 * CAP + l2) : -1;
    slot1a[s] = s1; slot2a[s] = s2;
    if (s1 >= 0) slot_tok[s1] = s;
    if (s2 >= 0) slot_tok[s2] = s;
  }

  // aux loss: per-thread partials -> wave shuffle-reduce -> 8 atomics/wave
  float part[NE];
  #pragma unroll
  for (int e = 0; e < NE; ++e) part[e] = 0.f;
  for (int s = tid; s < NT; s += 512) {
    const float* gr = gates + (size_t)s * NE;
    #pragma unroll
    for (int e = 0; e < NE; ++e) part[e] += gr[e];
  }
  #pragma unroll
  for (int off = 32; off > 0; off >>= 1) {
    #pragma unroll
    for (int e = 0; e < NE; ++e) part[e] += __shfl_down(part[e], off);
  }
  if (lane == 0) {
    #pragma unroll
    for (int e = 0; e < NE; ++e) atomicAdd(&gsum[e], part[e]);
  }
  __syncthreads();
  if (tid == 0) {
    float laux = 0.f;
    #pragma unroll
    for (int e = 0; e < NE; ++e)
      laux += (gsum[e] / (float)NT) * ((float)cnt1[e] / (float)NT);
    laux *= (float)(NE * NE) * 0.01f;
    out_tail[0] = laux;
  }
  if (tid < NE) out_tail[1 + tid] = (float)cnt1[tid];
}

// ------------- gather dispatched tokens -> bf16 A[E*C, H] -------------
__global__ __launch_bounds__(64) void gather_kernel(
    const float* __restrict__ x, const int* __restrict__ slot_tok,
    unsigned short* __restrict__ A)
{
  int slot = blockIdx.x;
  int t = slot_tok[slot];
  int tid = threadIdx.x;
  unsigned short* dst = A + (size_t)slot * HD;
  if (t >= 0) {
    const float* src = x + (size_t)t * HD;
    #pragma unroll
    for (int i = 0; i < 4; ++i) {
      int idx = i * 256 + tid * 4;
      float4 v = *(const float4*)(src + idx);
      uint2 p;
      p.x = (unsigned)f2bf(v.x) | ((unsigned)f2bf(v.y) << 16);
      p.y = (unsigned)f2bf(v.z) | ((unsigned)f2bf(v.w) << 16);
      *(uint2*)(dst + idx) = p;
    }
  } else {
    uint2 z; z.x = 0u; z.y = 0u;
    #pragma unroll
    for (int i = 0; i < 4; ++i) {
      int idx = i * 256 + tid * 4;
      *(uint2*)(dst + idx) = z;
    }
  }
}

// ---- fused GEMM: C[M,N] = A[M,K](bf16,k-contig) * W[K,N](fp32 original) ----
// B staging fuses transpose+cast: per K-tile, each thread does 2 tasks
// (n = tid&127, oct = tid>>7 and oct+2); each task = 8 lane-coalesced scalar
// loads down column n (256B/wave requests), f2bf pack, one ds_write_b128 into
// Bs[n][oct*8..] with BROW=40 pad (bank starts 20n%32 -> uniform).
// SPLITK: blockIdx.z = e*4+sk, fp32 partials out. GELU: bf16 gelu out.
template <bool SPLITK, bool GELU>
__global__ __launch_bounds__(256) void gemm_fused_kernel(
    const unsigned short* __restrict__ A, const float* __restrict__ W,
    void* __restrict__ Cout, int M, int N, int K)
{
  __shared__ unsigned short As[128 * 32];
  __shared__ unsigned short Bs[128 * BROW];
  const int tid = threadIdx.x;
  const int w = tid >> 6, lane = tid & 63;
  const int wm = (w >> 1) * 64, wn = (w & 1) * 64;
  const int quad = lane >> 4, l15 = lane & 15;
  const int m0 = blockIdx.y * 128, n0 = blockIdx.x * 128;

  size_t e; int sk, klen, kb;
  if (SPLITK) { e = blockIdx.z >> 2; sk = blockIdx.z & 3; klen = K / KSPLIT; kb = sk * klen; }
  else        { e = blockIdx.z;      sk = 0;              klen = K;          kb = 0; }

  const unsigned short* Ae = A + e * (size_t)M * K + kb;
  const float* We = W + e * (size_t)K * N + (size_t)kb * N + n0;

  // A staging (global_load_lds, width 16)
  const int lin0 = tid, lin1 = 256 + tid;
  const unsigned short* ga0 = Ae + (size_t)(m0 + (lin0 >> 2)) * K + (lin0 & 3) * 8;
  const unsigned short* ga1 = Ae + (size_t)(m0 + (lin1 >> 2)) * K + (lin1 & 3) * 8;
  char* sa0 = (char*)As + w * 1024;
  char* sa1 = (char*)As + 4096 + w * 1024;

  // B staging tasks
  const int bn = tid & 127;
  const int oct0 = tid >> 7;        // 0..1
  const int oct1 = oct0 + 2;        // 2..3
  const float* gw0 = We + (size_t)(oct0 * 8) * N + bn;
  const float* gw1 = We + (size_t)(oct1 * 8) * N + bn;
  unsigned short* bs0 = Bs + bn * BROW + oct0 * 8;
  unsigned short* bs1 = Bs + bn * BROW + oct1 * 8;

  f32x4_t acc[4][4];
  f32x4_t zz = {0.f, 0.f, 0.f, 0.f};
  #pragma unroll
  for (int mi = 0; mi < 4; ++mi)
    #pragma unroll
    for (int ni = 0; ni < 4; ++ni) acc[mi][ni] = zz;

  const int aoff0 = (wm + l15) * 32 + quad * 8;    // ushort offsets, As
  const int boff0 = (wn + l15) * BROW + quad * 8;  // ushort offsets, Bs

  for (int kt = 0; kt < klen; kt += 32) {
    load_lds16(ga0, sa0);
    load_lds16(ga1, sa1);
    ga0 += 32; ga1 += 32;
    // B: 16 scalar fp32 loads -> bf16 pack -> 2x ds_write_b128
    float b0[8], b1[8];
    #pragma unroll
    for (int j = 0; j < 8; ++j) { b0[j] = gw0[(size_t)j * N]; b1[j] = gw1[(size_t)j * N]; }
    gw0 += (size_t)32 * N; gw1 += (size_t)32 * N;
    uint4 p0, p1;
    p0.x = (unsigned)f2bf(b0[0]) | ((unsigned)f2bf(b0[1]) << 16);
    p0.y = (unsigned)f2bf(b0[2]) | ((unsigned)f2bf(b0[3]) << 16);
    p0.z = (unsigned)f2bf(b0[4]) | ((unsigned)f2bf(b0[5]) << 16);
    p0.w = (unsigned)f2bf(b0[6]) | ((unsigned)f2bf(b0[7]) << 16);
    p1.x = (unsigned)f2bf(b1[0]) | ((unsigned)f2bf(b1[1]) << 16);
    p1.y = (unsigned)f2bf(b1[2]) | ((unsigned)f2bf(b1[3]) << 16);
    p1.z = (unsigned)f2bf(b1[4]) | ((unsigned)f2bf(b1[5]) << 16);
    p1.w = (unsigned)f2bf(b1[6]) | ((unsigned)f2bf(b1[7]) << 16);
    *(uint4*)bs0 = p0;
    *(uint4*)bs1 = p1;
    __syncthreads();  // staging (vmcnt + lgkmcnt) drained
    bf16x8_t af[4], bf[4];
    #pragma unroll
    for (int mi = 0; mi < 4; ++mi)
      af[mi] = *(const bf16x8_t*)(As + aoff0 + mi * 16 * 32);
    #pragma unroll
    for (int ni = 0; ni < 4; ++ni)
      bf[ni] = *(const bf16x8_t*)(Bs + boff0 + ni * 16 * BROW);
    #pragma unroll
    for (int mi = 0; mi < 4; ++mi)
      #pragma unroll
      for (int ni = 0; ni < 4; ++ni)
        acc[mi][ni] = __builtin_amdgcn_mfma_f32_16x16x32_bf16(af[mi], bf[ni], acc[mi][ni], 0, 0, 0);
    __syncthreads();  // protect LDS from next-iter staging
  }

  // C/D layout: col = lane&15, row = quad*4 + r  [verified m89/m91]
  #pragma unroll
  for (int mi = 0; mi < 4; ++mi) {
    int rowb = m0 + wm + mi * 16 + quad * 4;
    #pragma unroll
    for (int ni = 0; ni < 4; ++ni) {
      int col = n0 + wn + ni * 16 + l15;
      #pragma unroll
      for (int r = 0; r < 4; ++r) {
        float v = acc[mi][ni][r];
        if (GELU) {
          size_t idx = e * (size_t)M * N + (size_t)(rowb + r) * N + col;
          ((unsigned short*)Cout)[idx] = f2bf(gelu_fast(v));
        } else {
          size_t idx = ((size_t)sk * NE + e) * (size_t)M * N + (size_t)(rowb + r) * N + col;
          ((float*)Cout)[idx] = v;
        }
      }
    }
  }
}

// ------------- combine: out[s] = g1*sum_p eop[slot1] + g2*sum_p eop[slot2] ----
__global__ __launch_bounds__(64) void combine_kernel(
    const float* __restrict__ eop, const float* __restrict__ g1a,
    const float* __restrict__ g2a, const int* __restrict__ slot1a,
    const int* __restrict__ slot2a, float* __restrict__ out)
{
  int s = blockIdx.x, tid = threadIdx.x;
  float g1 = g1a[s], g2 = g2a[s];
  int s1 = slot1a[s], s2 = slot2a[s];
  float m1 = (s1 < 0) ? 0.f : g1;
  float m2 = (s2 < 0) ? 0.f : g2;
  const float* r1 = eop + (size_t)(s1 < 0 ? 0 : s1) * HD;
  const float* r2 = eop + (size_t)(s2 < 0 ? 0 : s2) * HD;
  const size_t PSTRIDE = (size_t)NE * CAP * HD;
  #pragma unroll
  for (int i = 0; i < 4; ++i) {
    int idx = i * 256 + tid * 4;
    float ax = 0.f, ay = 0.f, az = 0.f, aw = 0.f;
    float bx = 0.f, by = 0.f, bz = 0.f, bw = 0.f;
    #pragma unroll
    for (int p = 0; p < KSPLIT; ++p) {
      float4 a = *(const float4*)(r1 + p * PSTRIDE + idx);
      float4 b = *(const float4*)(r2 + p * PSTRIDE + idx);
      ax += a.x; ay += a.y; az += a.z; aw += a.w;
      bx += b.x; by += b.y; bz += b.z; bw += b.w;
    }
    float4 o;
    o.x = m1 * ax + m2 * bx;
    o.y = m1 * ay + m2 * by;
    o.z = m1 * az + m2 * bz;
    o.w = m1 * aw + m2 * bw;
    *(float4*)(out + (size_t)s * HD + idx) = o;
  }
}

// ---------------- workspace layout (bytes) ----------------
#define OFF_GATES   ((size_t)0)            // 2048*8*4   = 65536
#define OFF_IDX1    ((size_t)65536)
#define OFF_IDX2    ((size_t)73728)
#define OFF_GATE1   ((size_t)81920)
#define OFF_GATE2   ((size_t)90112)
#define OFF_LOC1    ((size_t)98304)
#define OFF_LOC2    ((size_t)106496)
#define OFF_G1      ((size_t)114688)
#define OFF_G2      ((size_t)122880)
#define OFF_SLOT1   ((size_t)131072)
#define OFF_SLOT2   ((size_t)139264)
#define OFF_SLOTTOK ((size_t)147456)       // 4096*4 = 16384
#define OFF_A       ((size_t)262144)       // 8*512*1024*2  = 8388608
#define OFF_H       ((size_t)8650752)      // 8*512*4096*2  = 33554432
#define OFF_EOPART  ((size_t)42205184)     // 4*8*512*1024*4 = 67108864
#define WS_NEEDED   ((size_t)109314048)

extern "C" void kernel_launch(void* const* d_in, const int* in_sizes, int n_in,
                              void* d_out, int out_size, void* d_ws, size_t ws_size,
                              hipStream_t stream) {
  (void)in_sizes; (void)n_in; (void)out_size;
  if (ws_size < WS_NEEDED) return;  // workspace too small: fail cleanly

  const float* x  = (const float*)d_in[0];
  const float* wg = (const float*)d_in[1];
  const float* w1 = (const float*)d_in[2];
  const float* w2 = (const float*)d_in[3];
  char* ws = (char*)d_ws;
  float* out = (float*)d_out;

  float* gates = (float*)(ws + OFF_GATES);
  int*   idx1  = (int*)(ws + OFF_IDX1);
  int*   idx2  = (int*)(ws + OFF_IDX2);
  float* gate1 = (float*)(ws + OFF_GATE1);
  float* gate2 = (float*)(ws + OFF_GATE2);
  int*   loc1  = (int*)(ws + OFF_LOC1);
  int*   loc2  = (int*)(ws + OFF_LOC2);
  float* g1a   = (float*)(ws + OFF_G1);
  float* g2a   = (float*)(ws + OFF_G2);
  int*   slot1 = (int*)(ws + OFF_SLOT1);
  int*   slot2 = (int*)(ws + OFF_SLOT2);
  int*   stok  = (int*)(ws + OFF_SLOTTOK);
  unsigned short* Abf  = (unsigned short*)(ws + OFF_A);
  unsigned short* hbuf = (unsigned short*)(ws + OFF_H);
  float* eopart = (float*)(ws + OFF_EOPART);

  gating_kernel<<<NT / 4, 256, 0, stream>>>(x, wg, gates, idx1, idx2, gate1, gate2);
  scan_kernel<<<1, 512, 0, stream>>>(idx1, idx2, gate1, gate2, gates,
                                     loc1, loc2, g1a, g2a, slot1, slot2, stok,
                                     out + (size_t)NT * HD);
  gather_kernel<<<NE * CAP, 64, 0, stream>>>(x, stok, Abf);

  // h = gelu(A @ w1): M=512 N=4096 K=1024; w1 fp32 [K,N] consumed directly
  gemm_fused_kernel<false, true><<<dim3(FD / 128, CAP / 128, NE), 256, 0, stream>>>(
      Abf, w1, (void*)hbuf, CAP, FD, HD);
  // eo partials = h @ w2 (split-K=4): M=512 N=1024 K=4096; w2 fp32 [K,N]
  gemm_fused_kernel<true, false><<<dim3(HD / 128, CAP / 128, NE * KSPLIT), 256, 0, stream>>>(
      hbuf, w2, (void*)eopart, CAP, HD, FD);

  combine_kernel<<<NT, 64, 0, stream>>>(eopart, g1a, g2a, slot1, slot2, out);
}